// Round 4
// baseline (239.776 us; speedup 1.0000x reference)
//
#include <hip/hip_runtime.h>
#include <stdint.h>

// Problem constants
#define B_ 4
#define N_ 4096
#define D_ 256
#define M_ (B_*N_)   // 16384

typedef _Float16 f16;
typedef _Float16 f16x8 __attribute__((ext_vector_type(8)));
typedef float    f32x4  __attribute__((ext_vector_type(4)));
typedef float    f32x16 __attribute__((ext_vector_type(16)));

#define MFMA16(A,B,C) __builtin_amdgcn_mfma_f32_16x16x32_f16(A,B,C,0,0,0)
#define MFMA32(A,B,C) __builtin_amdgcn_mfma_f32_32x32x16_f16(A,B,C,0,0,0)

// workspace layout (bytes)
#define QH_OFF   0u            // Qh:   16384*256*2 = 8388608
#define KH_OFF   8388608u      // Kh:   8388608 (PRE-SWIZZLED)
#define VT_OFF   16777216u     // Vt:   [4][256][4096] f16 = 8388608
#define WFCH_OFF 25165824u     // Wfch: 131072 (DMA image, 8 slabs x 16KB)
#define WQS_OFF  25296896u     // Wqs:  262144 (DMA image, 16 half-slabs x 16KB)
#define WKS_OFF  25559040u
#define WVS_OFF  25821184u
#define OP_OFF   26083328u     // Opart: f16 [4][16384][256] = 33554432
#define ML_OFF   59637760u     // Ml: f32 [4][16384][2] = 524288

typedef __attribute__((address_space(3))) uint32_t lds_u32;
typedef __attribute__((address_space(1))) const uint32_t g_u32;

__device__ __forceinline__ void stage16(const f16* g, f16* lbase) {
    __builtin_amdgcn_global_load_lds((g_u32*)g, (lds_u32*)lbase, 16, 0, 0);
}
__device__ __forceinline__ uint32_t pk2(float a, float b) {
    union { f16 h[2]; uint32_t u; } x;
    x.h[0] = (f16)a; x.h[1] = (f16)b;
    return x.u;
}

// ---------------------------------------------------------------------------
// Kernel 1: weight conversion (unchanged from R12).
// ---------------------------------------------------------------------------
__global__ __launch_bounds__(256) void cvt_w(
    const float* __restrict__ Wq, const float* __restrict__ Wk,
    const float* __restrict__ Wv, const float* __restrict__ Wfc,
    f16* __restrict__ Wqs, f16* __restrict__ Wks, f16* __restrict__ Wvs,
    f16* __restrict__ Wfch)
{
    const int z = blockIdx.y;
    const float* W = (z==0) ? Wq : (z==1) ? Wk : (z==2) ? Wv : Wfc;
    int idx = (blockIdx.x * 256 + threadIdx.x) * 4;
    float4 v = *(const float4*)(W + idx);
    union { ushort4 u4; f16 h[4]; } hi, lo;
    float vv[4] = {v.x, v.y, v.z, v.w};
    #pragma unroll
    for (int j = 0; j < 4; j++) {
        hi.h[j] = (f16)vv[j];
        lo.h[j] = (f16)(vv[j] - (float)hi.h[j]);
    }
    int col = idx >> 8, k = idx & 255;
    int dc = k >> 5, c8 = (k >> 3) & 3, j = k & 7;
    int p  = c8 ^ ((col >> 2) & 3);
    if (z == 3) {
        *(ushort4*)(Wfch + dc*8192 + col*32 + p*8 + j) = hi.u4;
    } else {
        f16* Ws = (z==0) ? Wqs : (z==1) ? Wks : Wvs;
        int h  = col >> 7, cl = col & 127;
        int base = dc*16384 + h*8192 + cl*32 + p*8 + j;
        *(ushort4*)(Ws + base)        = hi.u4;
        *(ushort4*)(Ws + base + 4096) = lo.u4;
    }
}

// ---------------------------------------------------------------------------
// Kernel 2: QKV projection (unchanged from R12).
// ---------------------------------------------------------------------------
__global__ __launch_bounds__(256, 3) void proj_kernel(
    const float* __restrict__ x,
    const f16* __restrict__ Wqs, const f16* __restrict__ Wks,
    const f16* __restrict__ Wvs,
    const float* __restrict__ bq, const float* __restrict__ bk,
    const float* __restrict__ bv,
    f16* __restrict__ Qh, f16* __restrict__ Kh, f16* __restrict__ Vt)
{
    const int z = blockIdx.y;
    const f16*   Ws   = (z==0) ? Wqs : (z==1) ? Wks : Wvs;
    const float* bias = (z==0) ? bq  : (z==1) ? bk  : bv;

    __shared__ __align__(16) f16 Bs[2][8192];    // 32KB dbuf; VTs union below

    const int tid  = threadIdx.x;
    const int w    = tid >> 6;
    const int lane = tid & 63;
    const int l15  = lane & 15;
    const int q4   = lane >> 4;
    const int m0   = blockIdx.x * 64 + w * 16;
    const int rowA = m0 + l15;
    const int sw   = (l15 >> 2) & 3;             // B read swizzle key

    int s4[4];
    #pragma unroll
    for (int i = 0; i < 4; i++) s4[i] = (tid + i*256) * 8;

    f32x4 acc[16];
    #pragma unroll
    for (int nt = 0; nt < 16; nt++) acc[nt] = (f32x4){0.f,0.f,0.f,0.f};

    // prologue: DMA half-slab 0, load x chunk 0
    #pragma unroll
    for (int i = 0; i < 4; i++) stage16(Ws + s4[i], &Bs[0][0] + s4[i]);
    const float* xp = x + (size_t)rowA * 256;
    float4 a0 = *(const float4*)(xp + q4*8);
    float4 a1 = *(const float4*)(xp + q4*8 + 4);
    f16x8 ah, alo;

    for (int ph = 0; ph < 16; ph++) {
        const int cur = ph & 1;
        const int dc  = ph >> 1;
        const int h   = ph & 1;
        __syncthreads();                         // drains DMA(ph); prev reads done
        if (ph < 15) {                           // DMA half-slab ph+1
            const f16* src = Ws + (size_t)(ph+1)*8192;
            f16* dst = &Bs[cur ^ 1][0];
            #pragma unroll
            for (int i = 0; i < 4; i++) stage16(src + s4[i], dst + s4[i]);
        }
        if (h == 0) {                            // new dc: build hi/lo A-frags
            float av[8] = {a0.x,a0.y,a0.z,a0.w,a1.x,a1.y,a1.z,a1.w};
            #pragma unroll
            for (int j = 0; j < 8; j++) {
                ah[j]  = (f16)av[j];
                alo[j] = (f16)(av[j] - (float)ah[j]);
            }
        } else if (dc < 7) {                     // prefetch next x chunk
            a0 = *(const float4*)(xp + (dc+1)*32 + q4*8);
            a1 = *(const float4*)(xp + (dc+1)*32 + q4*8 + 4);
        }
        const f16* Bc = &Bs[cur][0];
        #pragma unroll
        for (int nt = 0; nt < 8; nt++) {
            const f16* bp = Bc + (nt*16 + l15)*32 + ((q4 ^ sw) << 3);
            f16x8 bh = *(const f16x8*)bp;
            f16x8 bl = *(const f16x8*)(bp + 4096);
            const int ng = h*8 + nt;
            acc[ng] = MFMA16(ah,  bl, acc[ng]);
            acc[ng] = MFMA16(alo, bh, acc[ng]);
            acc[ng] = MFMA16(ah,  bh, acc[ng]);
        }
    }

    if (z == 0) {
        #pragma unroll
        for (int nt = 0; nt < 16; nt++) {
            float bb = bias[nt*16 + l15];
            #pragma unroll
            for (int r = 0; r < 4; r++)
                Qh[(size_t)(m0 + q4*4 + r)*256 + nt*16 + l15] = (f16)(acc[nt][r] + bb);
        }
    } else if (z == 1) {
        // swizzled Kh image for attn's DMA staging
        const int cbase = (l15 >> 3);
        const int j     = l15 & 7;
        #pragma unroll
        for (int nt = 0; nt < 16; nt++) {
            float bb = bias[nt*16 + l15];
            int c = nt*2 + cbase;
            #pragma unroll
            for (int r = 0; r < 4; r++) {
                int m = m0 + q4*4 + r;
                Kh[(size_t)m*256 + (size_t)((c ^ (m & 7)) << 3) + j] = (f16)(acc[nt][r] + bb);
            }
        }
    } else {
        // V: transpose through LDS (unions with Bs), two 128-row passes
        uint32_t* VTs = (uint32_t*)&Bs[0][0];
        const int bb_ = m0 >> 12;
        const int n0  = (blockIdx.x * 64) & 4095;
        const int mloc = w*16 + q4*4;
        const int mc   = mloc >> 3;
        #pragma unroll
        for (int P = 0; P < 2; P++) {
            __syncthreads();
            #pragma unroll
            for (int nt = 0; nt < 8; nt++) {
                int e = P*128 + nt*16 + l15;
                float bv_ = bias[e];
                const f32x4& a = acc[P*8 + nt];
                uint32_t w0 = pk2(a[0]+bv_, a[1]+bv_);
                uint32_t w1 = pk2(a[2]+bv_, a[3]+bv_);
                int base = (e & 127)*36 + ((mc ^ (e & 7)) << 2) + ((q4*2) & 3);
                VTs[base]     = w0;
                VTs[base + 1] = w1;
            }
            __syncthreads();
            #pragma unroll
            for (int i = 0; i < 4; i++) {
                int el = w*32 + i*8 + (lane >> 3);
                int e  = P*128 + el;
                int nc = lane & 7;
                const f16* src = (const f16*)&VTs[el*36 + ((nc ^ (e & 7)) << 2)];
                f16x8 v = *(const f16x8*)src;
                *(f16x8*)(Vt + ((size_t)bb_*256 + e)*4096 + n0 + nc*8) = v;
            }
        }
    }
}

// ---------------------------------------------------------------------------
// Kernel 3: flash attention — R13 PROBE: inner loop byte-identical R9, but
// split into TWO dispatches of 256 blocks (sp pairs {0,1} and {2,3}).
// Purpose: (1) any kernel slower than an attn-half surfaces in the top-5
// counter window (proj/merge have never been visible); (2) A/B on attn's
// regime: 1 block/CU per dispatch removes cross-block overlap — if attn is
// LDS-BW/convoy-bound the halves sum < 100us, if latency-bound they sum more.
// Work assignment per block identical -> bit-identical outputs.
// ---------------------------------------------------------------------------
#define MARGIN 10.0f
__global__ __launch_bounds__(256, 2) void attn_kernel(
    const f16* __restrict__ Qh, const f16* __restrict__ Kh,
    const f16* __restrict__ Vt,
    f16* __restrict__ Opart, float* __restrict__ Ml,
    const int sp_base)
{
    __shared__ __align__(16) f16 SMEM[32768];     // Ks[2][8192] | Vs[2][8192]
    f16* Ks = SMEM;
    f16* Vs = SMEM + 16384;

    const int rest = blockIdx.x & 7;
    const int b   = rest >> 1;
    const int sp  = sp_base + (rest & 1);
    const int qt  = blockIdx.x >> 3;              // 0..31
    const int tid  = threadIdx.x;
    const int w    = tid >> 6;
    const int lane = tid & 63;
    const int l31  = lane & 31;                   // q column
    const int half = lane >> 5;
    const int qbase = qt * 128 + w * 32;          // wave's q-row base (incl. w)
    const int vx   = (l31 >> 2) & 3;              // V image swizzle key

    // Q as B-frags (16 steps of d): lane holds Q[q][8d]
    f16x8 qf[16];
    {
        const f16* qp = Qh + ((size_t)(b*4096 + qbase + l31))*256 + half*8;
        #pragma unroll
        for (int st = 0; st < 16; st++) qf[st] = *(const f16x8*)(qp + st*16);
    }

    f32x16 Oa[8];                                 // O^T d-tiles (C-layout)
    #pragma unroll
    for (int t = 0; t < 8; t++)
        #pragma unroll
        for (int r = 0; r < 16; r++) Oa[t][r] = 0.f;
    float mo = -3e38f, ls = 0.f;                  // per-lane (q = l31)

    const f16* kg0 = Kh + ((size_t)(b*4096 + sp*1024)) * 256;   // swizzled
    const f16* vg0 = Vt + ((size_t)b*256) * 4096 + sp*1024;

    int kslot[4], voff[4];
    #pragma unroll
    for (int i = 0; i < 4; i++) {
        int s = tid + i*256;
        kslot[i] = s * 8;
        int d = s >> 2;
        int kc = (s & 3) ^ ((s >> 4) & 3);        // image: pos = kc ^ ((d>>2)&3)
        voff[i] = d * 4096 + kc * 8;
    }

    // prologue: DMA K(0)
    #pragma unroll
    for (int i = 0; i < 4; i++) stage16(kg0 + kslot[i], Ks + kslot[i]);

    f16x8 bp0, bp1;                               // carried P^T B-frags

    for (int it = 0; it < 32; it++) {
        const int cur = it & 1;
        __syncthreads();                          // drains K(t), V(t-1) DMAs
        if (it + 1 < 32) {
            const f16* kg = kg0 + (size_t)(it+1) * 8192;
            f16* kl = Ks + (cur ^ 1) * 8192;
            #pragma unroll
            for (int i = 0; i < 4; i++) stage16(kg + kslot[i], kl + kslot[i]);
        }
        {
            const f16* vg = vg0 + it*32;
            f16* vl = Vs + cur * 8192;
            #pragma unroll
            for (int i = 0; i < 4; i++) stage16(vg + voff[i], vl + kslot[i]);
        }

        // S^T(t) interleaved with PV(t-1): 32 MFMAs
        const f16* krp = Ks + cur*8192 + l31*256;
        const f16* vpp = Vs + (cur^1)*8192 + l31*32;
        f32x16 sa;
        #pragma unroll
        for (int r = 0; r < 16; r++) sa[r] = 0.f;
        if (it > 0) {
            #pragma unroll
            for (int st = 0; st < 16; st++) {
                f16x8 ka = *(const f16x8*)(krp + (((st*2 + half) ^ (lane & 7)) << 3));
                sa = MFMA32(ka, qf[st], sa);
                int t = st >> 1, kh = st & 1;
                f16x8 va = *(const f16x8*)(vpp + t*1024 + (((half + kh*2) ^ vx) << 3));
                Oa[t] = MFMA32(va, kh ? bp1 : bp0, Oa[t]);
            }
        } else {
            #pragma unroll
            for (int st = 0; st < 16; st++) {
                f16x8 ka = *(const f16x8*)(krp + (((st*2 + half) ^ (lane & 7)) << 3));
                sa = MFMA32(ka, qf[st], sa);
            }
        }

        // per-lane hysteresis softmax (q = lane col)
        float tm = sa[0];
        #pragma unroll
        for (int r = 1; r < 16; r++) tm = fmaxf(tm, sa[r]);
        if (__any(tm > mo + MARGIN)) {
            float tmq = fmaxf(tm, __shfl_xor(tm, 32));
            float mn = fmaxf(mo, tmq);
            float al = __expf(mo - mn);
            mo = mn; ls *= al;
            #pragma unroll
            for (int t = 0; t < 8; t++)
                #pragma unroll
                for (int r = 0; r < 16; r++) Oa[t][r] *= al;
        }
        float p[16];
        #pragma unroll
        for (int r = 0; r < 16; r++) { p[r] = __expf(sa[r] - mo); ls += p[r]; }

        // build P^T B-frags: keys 16kh + [0..7](h=0) / [8..15](h=1)
        #pragma unroll
        for (int kh = 0; kh < 2; kh++) {
            uint32_t lo0 = pk2(p[8*kh+0], p[8*kh+1]);
            uint32_t lo1 = pk2(p[8*kh+2], p[8*kh+3]);
            uint32_t hi0 = pk2(p[8*kh+4], p[8*kh+5]);
            uint32_t hi1 = pk2(p[8*kh+6], p[8*kh+7]);
            uint32_t s0 = half ? lo0 : hi0;
            uint32_t s1 = half ? lo1 : hi1;
            uint32_t r0 = __shfl_xor(s0, 32);
            uint32_t r1 = __shfl_xor(s1, 32);
            uint32_t k0 = half ? hi0 : lo0;
            uint32_t k1 = half ? hi1 : lo1;
            union { uint32_t u[4]; f16x8 v; } bb;
            bb.u[0] = half ? r0 : k0;
            bb.u[1] = half ? r1 : k1;
            bb.u[2] = half ? k0 : r0;
            bb.u[3] = half ? k1 : r1;
            if (kh == 0) bp0 = bb.v; else bp1 = bb.v;
        }
    }

    // final PV(31): drain V(31) DMA, then consume
    __syncthreads();
    {
        const f16* vpp = Vs + 8192 + l31*32;      // V(31) in Vs[1]
        #pragma unroll
        for (int t = 0; t < 8; t++) {
            #pragma unroll
            for (int kh = 0; kh < 2; kh++) {
                f16x8 va = *(const f16x8*)(vpp + t*1024 + (((half + kh*2) ^ vx) << 3));
                Oa[t] = MFMA32(va, kh ? bp1 : bp0, Oa[t]);
            }
        }
    }
    __syncthreads();                              // all waves done with SMEM tiles

    // epilogue: l across half-pair, normalize, un-transpose via per-wave LDS
    float l = ls + __shfl_xor(ls, 32);
    float inv = 1.0f / l;
    f16* tb = SMEM + w * 8192;                    // 16KB per wave
    #pragma unroll
    for (int t = 0; t < 8; t++) {
        #pragma unroll
        for (int rp = 0; rp < 8; rp++) {
            int r0 = rp * 2;
            int d  = (r0 & 3) + 8*(r0 >> 2) + 4*half + t*32;
            int c  = d >> 3, j = d & 7;
            uint32_t wv = pk2(Oa[t][r0]*inv, Oa[t][r0+1]*inv);
            *(uint32_t*)(tb + l31*256 + ((c ^ (l31 & 7)) << 3) + (j & 6)) = wv;
        }
    }
    // coalesced read-back + global store (per-wave region, rows = qbase+q)
    f16* opb = Opart + ((size_t)sp*M_ + b*4096 + qbase) * 256;
    #pragma unroll
    for (int i = 0; i < 16; i++) {
        int q = (i & 3)*8 + (lane >> 3);
        int c = (i >> 2)*8 + (lane & 7);
        f16x8 v = *(const f16x8*)(tb + q*256 + ((c ^ (q & 7)) << 3));
        *(f16x8*)(opb + (size_t)q*256 + c*8) = v;
    }
    if (half == 0) {
        size_t mrow = (size_t)sp*M_ + b*4096 + qbase + l31;
        Ml[mrow*2]     = mo;
        Ml[mrow*2 + 1] = l;
    }
}

// ---------------------------------------------------------------------------
// Kernel 4: merge 4 normalized k-quarter partials + FC + bias (unchanged R12).
// ---------------------------------------------------------------------------
__global__ __launch_bounds__(256, 2) void merge_fc_kernel(
    const f16* __restrict__ Opart, const float* __restrict__ Ml,
    const f16* __restrict__ Wfci, const float* __restrict__ bfc,
    float* __restrict__ out)
{
    __shared__ __align__(16) f16 Bs[2][8192];    // 2 x 16KB slabs

    const int tid  = threadIdx.x;
    const int w    = tid >> 6;
    const int lane = tid & 63;
    const int l15  = lane & 15;
    const int q4   = lane >> 4;
    const int rw   = w >> 1;                     // row-half of the block
    const int nh   = w & 1;                      // nt-half
    const int m0   = blockIdx.x * 32 + rw * 16;
    const int rowA = m0 + l15;
    const int sw   = (l15 >> 2) & 3;             // B read swizzle key

    int s4[4];
    #pragma unroll
    for (int i = 0; i < 4; i++) s4[i] = (tid + i*256) * 8;

    float mv[4], lv[4];
    #pragma unroll
    for (int p = 0; p < 4; p++) {
        mv[p] = Ml[((size_t)p*M_ + rowA)*2];
        lv[p] = Ml[((size_t)p*M_ + rowA)*2 + 1];
    }
    float mm = fmaxf(fmaxf(mv[0], mv[1]), fmaxf(mv[2], mv[3]));
    float cw[4], den = 0.f;
    #pragma unroll
    for (int p = 0; p < 4; p++) { cw[p] = __expf(mv[p] - mm) * lv[p]; den += cw[p]; }
    float invd = 1.0f / den;
    #pragma unroll
    for (int p = 0; p < 4; p++) cw[p] *= invd;

    // prologue: DMA slab 0, prefetch Opart frags for dc=0
    #pragma unroll
    for (int i = 0; i < 4; i++) stage16(Wfci + s4[i], &Bs[0][0] + s4[i]);
    const f16* opb = Opart + (size_t)rowA*256 + q4*8;
    f16x8 of[4];
    #pragma unroll
    for (int p = 0; p < 4; p++) of[p] = *(const f16x8*)(opb + (size_t)p*M_*256);

    f32x4 acc[8];
    #pragma unroll
    for (int nt = 0; nt < 8; nt++) acc[nt] = (f32x4){0.f,0.f,0.f,0.f};

    for (int dc = 0; dc < 8; dc++) {
        const int cur = dc & 1;
        __syncthreads();                         // drains DMA(dc); prev reads done
        if (dc < 7) {
            const f16* src = Wfci + (size_t)(dc+1)*8192;
            f16* dst = &Bs[cur ^ 1][0];
            #pragma unroll
            for (int i = 0; i < 4; i++) stage16(src + s4[i], dst + s4[i]);
        }
        // weighted merge of the 4 partials -> A-frag
        float v[8] = {};
        #pragma unroll
        for (int p = 0; p < 4; p++)
            #pragma unroll
            for (int j = 0; j < 8; j++) v[j] += cw[p] * (float)of[p][j];
        f16x8 af;
        #pragma unroll
        for (int j = 0; j < 8; j++) af[j] = (f16)v[j];
        if (dc < 7) {                            // prefetch next Opart frags
            #pragma unroll
            for (int p = 0; p < 4; p++)
                of[p] = *(const f16x8*)(opb + (size_t)p*M_*256 + (dc+1)*32);
        }
        const f16* Bc = &Bs[cur][0];
        #pragma unroll
        for (int nt = 0; nt < 8; nt++) {
            const int ng = nh*8 + nt;
            f16x8 bf = *(const f16x8*)(Bc + (ng*16 + l15)*32 + ((q4 ^ sw) << 3));
            acc[nt] = MFMA16(af, bf, acc[nt]);
        }
    }
    #pragma unroll
    for (int nt = 0; nt < 8; nt++) {
        const int ng = nh*8 + nt;
        float bias = bfc[ng*16 + l15];
        #pragma unroll
        for (int r = 0; r < 4; r++)
            out[(size_t)(m0 + q4*4 + r) * 256 + ng*16 + l15] = acc[nt][r] + bias;
    }
}

// ---------------------------------------------------------------------------
extern "C" void kernel_launch(void* const* d_in, const int* in_sizes, int n_in,
                              void* d_out, int out_size, void* d_ws, size_t ws_size,
                              hipStream_t stream)
{
    const float* x   = (const float*)d_in[0];
    const float* Wq  = (const float*)d_in[1];
    const float* bq  = (const float*)d_in[2];
    const float* Wk  = (const float*)d_in[3];
    const float* bk  = (const float*)d_in[4];
    const float* Wv  = (const float*)d_in[5];
    const float* bv  = (const float*)d_in[6];
    const float* Wfc = (const float*)d_in[7];
    const float* bfc = (const float*)d_in[8];
    float* out = (float*)d_out;

    char* ws = (char*)d_ws;
    f16*   Qh    = (f16*)(ws + QH_OFF);
    f16*   Kh    = (f16*)(ws + KH_OFF);
    f16*   Vt    = (f16*)(ws + VT_OFF);
    f16*   Wfch  = (f16*)(ws + WFCH_OFF);
    f16*   Wqs   = (f16*)(ws + WQS_OFF);
    f16*   Wks   = (f16*)(ws + WKS_OFF);
    f16*   Wvs   = (f16*)(ws + WVS_OFF);
    f16*   Opart = (f16*)(ws + OP_OFF);
    float* Ml    = (float*)(ws + ML_OFF);

    cvt_w<<<dim3(64, 4), 256, 0, stream>>>(Wq, Wk, Wv, Wfc, Wqs, Wks, Wvs, Wfch);
    proj_kernel<<<dim3(256, 3), 256, 0, stream>>>(x, Wqs, Wks, Wvs, bq, bk, bv, Qh, Kh, Vt);
    attn_kernel<<<256, 256, 0, stream>>>(Qh, Kh, Vt, Opart, Ml, 0);
    attn_kernel<<<256, 256, 0, stream>>>(Qh, Kh, Vt, Opart, Ml, 2);
    merge_fc_kernel<<<512, 256, 0, stream>>>(Opart, Ml, Wfch, bfc, out);
}

// Round 5
// 215.917 us; speedup vs baseline: 1.1105x; 1.1105x over previous
//
#include <hip/hip_runtime.h>
#include <stdint.h>

// Problem constants
#define B_ 4
#define N_ 4096
#define D_ 256
#define M_ (B_*N_)   // 16384

typedef _Float16 f16;
typedef _Float16 f16x8 __attribute__((ext_vector_type(8)));
typedef float    f32x4  __attribute__((ext_vector_type(4)));
typedef float    f32x16 __attribute__((ext_vector_type(16)));

#define MFMA16(A,B,C) __builtin_amdgcn_mfma_f32_16x16x32_f16(A,B,C,0,0,0)
#define MFMA32(A,B,C) __builtin_amdgcn_mfma_f32_32x32x16_f16(A,B,C,0,0,0)

// workspace layout (bytes) — R14: W images deleted (conversion fused into
// proj/merge staging); cvt_w kernel removed.
#define QH_OFF   0u            // Qh:   16384*256*2 = 8388608
#define KH_OFF   8388608u      // Kh:   8388608 (PRE-SWIZZLED)
#define VT_OFF   16777216u     // Vt:   [4][256][4096] f16 = 8388608
#define OP_OFF   25165824u     // Opart: f16 [4][16384][256] = 33554432
#define ML_OFF   58720256u     // Ml: f32 [4][16384][2] = 524288

typedef __attribute__((address_space(3))) uint32_t lds_u32;
typedef __attribute__((address_space(1))) const uint32_t g_u32;

__device__ __forceinline__ void stage16(const f16* g, f16* lbase) {
    __builtin_amdgcn_global_load_lds((g_u32*)g, (lds_u32*)lbase, 16, 0, 0);
}
__device__ __forceinline__ uint32_t pk2(float a, float b) {
    union { f16 h[2]; uint32_t u; } x;
    x.h[0] = (f16)a; x.h[1] = (f16)b;
    return x.u;
}

// ---------------------------------------------------------------------------
// R14 fused W staging (replaces cvt_w + DMA images).
// Produces in LDS the EXACT image cvt_w used to write:
//   phase ph (dc=ph>>1, h=ph&1): dst[cl*32 + p*8 + j] = hi of
//     W[(h*128+cl)*256 + dc*32 + (p ^ ((cl>>2)&3))*8 + j],  lo at +4096.
// Readers (proj MFMA loop) are untouched. hi/lo math identical to cvt_w.
// ---------------------------------------------------------------------------
__device__ __forceinline__ void stage_w_phase(
    const float* __restrict__ W, int ph, f16* dst, int tid)
{
    const int dc = ph >> 1, h = ph & 1;
    #pragma unroll
    for (int i = 0; i < 2; i++) {
        int u  = tid*2 + i;                 // 512 units of (cl,p)
        int cl = u >> 2, p = u & 3;
        int c8 = p ^ ((cl >> 2) & 3);
        const float* src = W + (size_t)(h*128 + cl)*256 + dc*32 + c8*8;
        float4 v0 = *(const float4*)(src);
        float4 v1 = *(const float4*)(src + 4);
        float vv[8] = {v0.x,v0.y,v0.z,v0.w,v1.x,v1.y,v1.z,v1.w};
        f16x8 hi, lo;
        #pragma unroll
        for (int j = 0; j < 8; j++) {
            hi[j] = (f16)vv[j];
            lo[j] = (f16)(vv[j] - (float)hi[j]);
        }
        *(f16x8*)(dst + cl*32 + p*8)        = hi;
        *(f16x8*)(dst + cl*32 + p*8 + 4096) = lo;
    }
}

// merge's Wfc image (hi only): slab dc: dst[col*32 + p*8 + j] = hi of
//   Wfc[col*256 + dc*32 + (p ^ ((col>>2)&3))*8 + j]
__device__ __forceinline__ void stage_wfc_phase(
    const float* __restrict__ W, int dc, f16* dst, int tid)
{
    #pragma unroll
    for (int i = 0; i < 4; i++) {
        int u   = tid*4 + i;                // 1024 units of (col,p)
        int col = u >> 2, p = u & 3;
        int c8  = p ^ ((col >> 2) & 3);
        const float* src = W + (size_t)col*256 + dc*32 + c8*8;
        float4 v0 = *(const float4*)(src);
        float4 v1 = *(const float4*)(src + 4);
        float vv[8] = {v0.x,v0.y,v0.z,v0.w,v1.x,v1.y,v1.z,v1.w};
        f16x8 hi;
        #pragma unroll
        for (int j = 0; j < 8; j++) hi[j] = (f16)vv[j];
        *(f16x8*)(dst + col*32 + p*8) = hi;
    }
}

// ---------------------------------------------------------------------------
// Kernel 1: QKV projection (f16 MFMA hi/lo), reg-staged B with inline f32
// conversion (R14 — cvt_w fused in). MFMA loop / outputs identical to R12.
// ---------------------------------------------------------------------------
__global__ __launch_bounds__(256, 3) void proj_kernel(
    const float* __restrict__ x,
    const float* __restrict__ Wq, const float* __restrict__ Wk,
    const float* __restrict__ Wv,
    const float* __restrict__ bq, const float* __restrict__ bk,
    const float* __restrict__ bv,
    f16* __restrict__ Qh, f16* __restrict__ Kh, f16* __restrict__ Vt)
{
    const int z = blockIdx.y;
    const float* W    = (z==0) ? Wq : (z==1) ? Wk : Wv;
    const float* bias = (z==0) ? bq : (z==1) ? bk : bv;

    __shared__ __align__(16) f16 Bs[2][8192];    // 32KB dbuf; VTs union below

    const int tid  = threadIdx.x;
    const int w    = tid >> 6;
    const int lane = tid & 63;
    const int l15  = lane & 15;
    const int q4   = lane >> 4;
    const int m0   = blockIdx.x * 64 + w * 16;
    const int rowA = m0 + l15;
    const int sw   = (l15 >> 2) & 3;             // B read swizzle key

    f32x4 acc[16];
    #pragma unroll
    for (int nt = 0; nt < 16; nt++) acc[nt] = (f32x4){0.f,0.f,0.f,0.f};

    // prologue: stage phase 0, load x chunk 0
    stage_w_phase(W, 0, &Bs[0][0], tid);
    const float* xp = x + (size_t)rowA * 256;
    float4 a0 = *(const float4*)(xp + q4*8);
    float4 a1 = *(const float4*)(xp + q4*8 + 4);
    f16x8 ah, alo;

    for (int ph = 0; ph < 16; ph++) {
        const int cur = ph & 1;
        const int dc  = ph >> 1;
        const int h   = ph & 1;
        __syncthreads();                         // phase ph image visible
        if (ph < 15)                             // stage phase ph+1 (other buf)
            stage_w_phase(W, ph+1, &Bs[cur ^ 1][0], tid);
        if (h == 0) {                            // new dc: build hi/lo A-frags
            float av[8] = {a0.x,a0.y,a0.z,a0.w,a1.x,a1.y,a1.z,a1.w};
            #pragma unroll
            for (int j = 0; j < 8; j++) {
                ah[j]  = (f16)av[j];
                alo[j] = (f16)(av[j] - (float)ah[j]);
            }
        } else if (dc < 7) {                     // prefetch next x chunk
            a0 = *(const float4*)(xp + (dc+1)*32 + q4*8);
            a1 = *(const float4*)(xp + (dc+1)*32 + q4*8 + 4);
        }
        const f16* Bc = &Bs[cur][0];
        #pragma unroll
        for (int nt = 0; nt < 8; nt++) {
            const f16* bp = Bc + (nt*16 + l15)*32 + ((q4 ^ sw) << 3);
            f16x8 bh = *(const f16x8*)bp;
            f16x8 bl = *(const f16x8*)(bp + 4096);
            const int ng = h*8 + nt;
            acc[ng] = MFMA16(ah,  bl, acc[ng]);
            acc[ng] = MFMA16(alo, bh, acc[ng]);
            acc[ng] = MFMA16(ah,  bh, acc[ng]);
        }
    }

    if (z == 0) {
        #pragma unroll
        for (int nt = 0; nt < 16; nt++) {
            float bb = bias[nt*16 + l15];
            #pragma unroll
            for (int r = 0; r < 4; r++)
                Qh[(size_t)(m0 + q4*4 + r)*256 + nt*16 + l15] = (f16)(acc[nt][r] + bb);
        }
    } else if (z == 1) {
        // swizzled Kh image for attn's DMA staging
        const int cbase = (l15 >> 3);
        const int j     = l15 & 7;
        #pragma unroll
        for (int nt = 0; nt < 16; nt++) {
            float bb = bias[nt*16 + l15];
            int c = nt*2 + cbase;
            #pragma unroll
            for (int r = 0; r < 4; r++) {
                int m = m0 + q4*4 + r;
                Kh[(size_t)m*256 + (size_t)((c ^ (m & 7)) << 3) + j] = (f16)(acc[nt][r] + bb);
            }
        }
    } else {
        // V: transpose through LDS (unions with Bs), two 128-row passes
        uint32_t* VTs = (uint32_t*)&Bs[0][0];
        const int bb_ = m0 >> 12;
        const int n0  = (blockIdx.x * 64) & 4095;
        const int mloc = w*16 + q4*4;
        const int mc   = mloc >> 3;
        #pragma unroll
        for (int P = 0; P < 2; P++) {
            __syncthreads();
            #pragma unroll
            for (int nt = 0; nt < 8; nt++) {
                int e = P*128 + nt*16 + l15;
                float bv_ = bias[e];
                const f32x4& a = acc[P*8 + nt];
                uint32_t w0 = pk2(a[0]+bv_, a[1]+bv_);
                uint32_t w1 = pk2(a[2]+bv_, a[3]+bv_);
                int base = (e & 127)*36 + ((mc ^ (e & 7)) << 2) + ((q4*2) & 3);
                VTs[base]     = w0;
                VTs[base + 1] = w1;
            }
            __syncthreads();
            #pragma unroll
            for (int i = 0; i < 4; i++) {
                int el = w*32 + i*8 + (lane >> 3);
                int e  = P*128 + el;
                int nc = lane & 7;
                const f16* src = (const f16*)&VTs[el*36 + ((nc ^ (e & 7)) << 2)];
                f16x8 v = *(const f16x8*)src;
                *(f16x8*)(Vt + ((size_t)bb_*256 + e)*4096 + n0 + nc*8) = v;
            }
        }
    }
}

// ---------------------------------------------------------------------------
// Kernel 2: flash attention, TRANSPOSED compute with 32x32x16 MFMA.
// R14 = verified R9/R12 body, single 512-block dispatch (R13 probe showed
// halves cost 70+70 vs 100 fused: latency-bound, concurrency helps).
// ---------------------------------------------------------------------------
#define MARGIN 10.0f
__global__ __launch_bounds__(256, 2) void attn_kernel(
    const f16* __restrict__ Qh, const f16* __restrict__ Kh,
    const f16* __restrict__ Vt,
    f16* __restrict__ Opart, float* __restrict__ Ml)
{
    __shared__ __align__(16) f16 SMEM[32768];     // Ks[2][8192] | Vs[2][8192]
    f16* Ks = SMEM;
    f16* Vs = SMEM + 16384;

    const int combo = blockIdx.x & 15;
    const int b   = combo >> 2;
    const int sp  = combo & 3;
    const int qt  = blockIdx.x >> 4;              // 0..31
    const int tid  = threadIdx.x;
    const int w    = tid >> 6;
    const int lane = tid & 63;
    const int l31  = lane & 31;                   // q column
    const int half = lane >> 5;
    const int qbase = qt * 128 + w * 32;          // wave's q-row base (incl. w)
    const int vx   = (l31 >> 2) & 3;              // V image swizzle key

    // Q as B-frags (16 steps of d): lane holds Q[q][8d]
    f16x8 qf[16];
    {
        const f16* qp = Qh + ((size_t)(b*4096 + qbase + l31))*256 + half*8;
        #pragma unroll
        for (int st = 0; st < 16; st++) qf[st] = *(const f16x8*)(qp + st*16);
    }

    f32x16 Oa[8];                                 // O^T d-tiles (C-layout)
    #pragma unroll
    for (int t = 0; t < 8; t++)
        #pragma unroll
        for (int r = 0; r < 16; r++) Oa[t][r] = 0.f;
    float mo = -3e38f, ls = 0.f;                  // per-lane (q = l31)

    const f16* kg0 = Kh + ((size_t)(b*4096 + sp*1024)) * 256;   // swizzled
    const f16* vg0 = Vt + ((size_t)b*256) * 4096 + sp*1024;

    int kslot[4], voff[4];
    #pragma unroll
    for (int i = 0; i < 4; i++) {
        int s = tid + i*256;
        kslot[i] = s * 8;
        int d = s >> 2;
        int kc = (s & 3) ^ ((s >> 4) & 3);        // image: pos = kc ^ ((d>>2)&3)
        voff[i] = d * 4096 + kc * 8;
    }

    // prologue: DMA K(0)
    #pragma unroll
    for (int i = 0; i < 4; i++) stage16(kg0 + kslot[i], Ks + kslot[i]);

    f16x8 bp0, bp1;                               // carried P^T B-frags

    for (int it = 0; it < 32; it++) {
        const int cur = it & 1;
        __syncthreads();                          // drains K(t), V(t-1) DMAs
        if (it + 1 < 32) {
            const f16* kg = kg0 + (size_t)(it+1) * 8192;
            f16* kl = Ks + (cur ^ 1) * 8192;
            #pragma unroll
            for (int i = 0; i < 4; i++) stage16(kg + kslot[i], kl + kslot[i]);
        }
        {
            const f16* vg = vg0 + it*32;
            f16* vl = Vs + cur * 8192;
            #pragma unroll
            for (int i = 0; i < 4; i++) stage16(vg + voff[i], vl + kslot[i]);
        }

        // S^T(t) interleaved with PV(t-1): 32 MFMAs
        const f16* krp = Ks + cur*8192 + l31*256;
        const f16* vpp = Vs + (cur^1)*8192 + l31*32;
        f32x16 sa;
        #pragma unroll
        for (int r = 0; r < 16; r++) sa[r] = 0.f;
        if (it > 0) {
            #pragma unroll
            for (int st = 0; st < 16; st++) {
                f16x8 ka = *(const f16x8*)(krp + (((st*2 + half) ^ (lane & 7)) << 3));
                sa = MFMA32(ka, qf[st], sa);
                int t = st >> 1, kh = st & 1;
                f16x8 va = *(const f16x8*)(vpp + t*1024 + (((half + kh*2) ^ vx) << 3));
                Oa[t] = MFMA32(va, kh ? bp1 : bp0, Oa[t]);
            }
        } else {
            #pragma unroll
            for (int st = 0; st < 16; st++) {
                f16x8 ka = *(const f16x8*)(krp + (((st*2 + half) ^ (lane & 7)) << 3));
                sa = MFMA32(ka, qf[st], sa);
            }
        }

        // per-lane hysteresis softmax (q = lane col)
        float tm = sa[0];
        #pragma unroll
        for (int r = 1; r < 16; r++) tm = fmaxf(tm, sa[r]);
        if (__any(tm > mo + MARGIN)) {
            float tmq = fmaxf(tm, __shfl_xor(tm, 32));
            float mn = fmaxf(mo, tmq);
            float al = __expf(mo - mn);
            mo = mn; ls *= al;
            #pragma unroll
            for (int t = 0; t < 8; t++)
                #pragma unroll
                for (int r = 0; r < 16; r++) Oa[t][r] *= al;
        }
        float p[16];
        #pragma unroll
        for (int r = 0; r < 16; r++) { p[r] = __expf(sa[r] - mo); ls += p[r]; }

        // build P^T B-frags: keys 16kh + [0..7](h=0) / [8..15](h=1)
        #pragma unroll
        for (int kh = 0; kh < 2; kh++) {
            uint32_t lo0 = pk2(p[8*kh+0], p[8*kh+1]);
            uint32_t lo1 = pk2(p[8*kh+2], p[8*kh+3]);
            uint32_t hi0 = pk2(p[8*kh+4], p[8*kh+5]);
            uint32_t hi1 = pk2(p[8*kh+6], p[8*kh+7]);
            uint32_t s0 = half ? lo0 : hi0;
            uint32_t s1 = half ? lo1 : hi1;
            uint32_t r0 = __shfl_xor(s0, 32);
            uint32_t r1 = __shfl_xor(s1, 32);
            uint32_t k0 = half ? hi0 : lo0;
            uint32_t k1 = half ? hi1 : lo1;
            union { uint32_t u[4]; f16x8 v; } bb;
            bb.u[0] = half ? r0 : k0;
            bb.u[1] = half ? r1 : k1;
            bb.u[2] = half ? k0 : r0;
            bb.u[3] = half ? k1 : r1;
            if (kh == 0) bp0 = bb.v; else bp1 = bb.v;
        }
    }

    // final PV(31): drain V(31) DMA, then consume
    __syncthreads();
    {
        const f16* vpp = Vs + 8192 + l31*32;      // V(31) in Vs[1]
        #pragma unroll
        for (int t = 0; t < 8; t++) {
            #pragma unroll
            for (int kh = 0; kh < 2; kh++) {
                f16x8 va = *(const f16x8*)(vpp + t*1024 + (((half + kh*2) ^ vx) << 3));
                Oa[t] = MFMA32(va, kh ? bp1 : bp0, Oa[t]);
            }
        }
    }
    __syncthreads();                              // all waves done with SMEM tiles

    // epilogue: l across half-pair, normalize, un-transpose via per-wave LDS
    float l = ls + __shfl_xor(ls, 32);
    float inv = 1.0f / l;
    f16* tb = SMEM + w * 8192;                    // 16KB per wave
    #pragma unroll
    for (int t = 0; t < 8; t++) {
        #pragma unroll
        for (int rp = 0; rp < 8; rp++) {
            int r0 = rp * 2;
            int d  = (r0 & 3) + 8*(r0 >> 2) + 4*half + t*32;
            int c  = d >> 3, j = d & 7;
            uint32_t wv = pk2(Oa[t][r0]*inv, Oa[t][r0+1]*inv);
            *(uint32_t*)(tb + l31*256 + ((c ^ (l31 & 7)) << 3) + (j & 6)) = wv;
        }
    }
    // coalesced read-back + global store (per-wave region, rows = qbase+q)
    f16* opb = Opart + ((size_t)sp*M_ + b*4096 + qbase) * 256;
    #pragma unroll
    for (int i = 0; i < 16; i++) {
        int q = (i & 3)*8 + (lane >> 3);
        int c = (i >> 2)*8 + (lane & 7);
        f16x8 v = *(const f16x8*)(tb + q*256 + ((c ^ (q & 7)) << 3));
        *(f16x8*)(opb + (size_t)q*256 + c*8) = v;
    }
    if (half == 0) {
        size_t mrow = (size_t)sp*M_ + b*4096 + qbase + l31;
        Ml[mrow*2]     = mo;
        Ml[mrow*2 + 1] = l;
    }
}

// ---------------------------------------------------------------------------
// Kernel 3: merge 4 normalized k-quarter partials + FC + bias.
// R14: Wfc conversion fused into staging (reg-staged f32 -> f16 hi image).
// Grid/MFMA structure unchanged from R12 (512 blocks, 2/CU).
// ---------------------------------------------------------------------------
__global__ __launch_bounds__(256, 2) void merge_fc_kernel(
    const f16* __restrict__ Opart, const float* __restrict__ Ml,
    const float* __restrict__ Wfc, const float* __restrict__ bfc,
    float* __restrict__ out)
{
    __shared__ __align__(16) f16 Bs[2][8192];    // 2 x 16KB slabs

    const int tid  = threadIdx.x;
    const int w    = tid >> 6;
    const int lane = tid & 63;
    const int l15  = lane & 15;
    const int q4   = lane >> 4;
    const int rw   = w >> 1;                     // row-half of the block
    const int nh   = w & 1;                      // nt-half
    const int m0   = blockIdx.x * 32 + rw * 16;
    const int rowA = m0 + l15;
    const int sw   = (l15 >> 2) & 3;             // B read swizzle key

    float mv[4], lv[4];
    #pragma unroll
    for (int p = 0; p < 4; p++) {
        mv[p] = Ml[((size_t)p*M_ + rowA)*2];
        lv[p] = Ml[((size_t)p*M_ + rowA)*2 + 1];
    }
    float mm = fmaxf(fmaxf(mv[0], mv[1]), fmaxf(mv[2], mv[3]));
    float cw[4], den = 0.f;
    #pragma unroll
    for (int p = 0; p < 4; p++) { cw[p] = __expf(mv[p] - mm) * lv[p]; den += cw[p]; }
    float invd = 1.0f / den;
    #pragma unroll
    for (int p = 0; p < 4; p++) cw[p] *= invd;

    // prologue: stage slab 0, prefetch Opart frags for dc=0
    stage_wfc_phase(Wfc, 0, &Bs[0][0], tid);
    const f16* opb = Opart + (size_t)rowA*256 + q4*8;
    f16x8 of[4];
    #pragma unroll
    for (int p = 0; p < 4; p++) of[p] = *(const f16x8*)(opb + (size_t)p*M_*256);

    f32x4 acc[8];
    #pragma unroll
    for (int nt = 0; nt < 8; nt++) acc[nt] = (f32x4){0.f,0.f,0.f,0.f};

    for (int dc = 0; dc < 8; dc++) {
        const int cur = dc & 1;
        __syncthreads();                         // slab dc image visible
        if (dc < 7)
            stage_wfc_phase(Wfc, dc+1, &Bs[cur ^ 1][0], tid);
        // weighted merge of the 4 partials -> A-frag
        float v[8] = {};
        #pragma unroll
        for (int p = 0; p < 4; p++)
            #pragma unroll
            for (int j = 0; j < 8; j++) v[j] += cw[p] * (float)of[p][j];
        f16x8 af;
        #pragma unroll
        for (int j = 0; j < 8; j++) af[j] = (f16)v[j];
        if (dc < 7) {                            // prefetch next Opart frags
            #pragma unroll
            for (int p = 0; p < 4; p++)
                of[p] = *(const f16x8*)(opb + (size_t)p*M_*256 + (dc+1)*32);
        }
        const f16* Bc = &Bs[cur][0];
        #pragma unroll
        for (int nt = 0; nt < 8; nt++) {
            const int ng = nh*8 + nt;
            f16x8 bf = *(const f16x8*)(Bc + (ng*16 + l15)*32 + ((q4 ^ sw) << 3));
            acc[nt] = MFMA16(af, bf, acc[nt]);
        }
    }
    #pragma unroll
    for (int nt = 0; nt < 8; nt++) {
        const int ng = nh*8 + nt;
        float bias = bfc[ng*16 + l15];
        #pragma unroll
        for (int r = 0; r < 4; r++)
            out[(size_t)(m0 + q4*4 + r) * 256 + ng*16 + l15] = acc[nt][r] + bias;
    }
}

// ---------------------------------------------------------------------------
extern "C" void kernel_launch(void* const* d_in, const int* in_sizes, int n_in,
                              void* d_out, int out_size, void* d_ws, size_t ws_size,
                              hipStream_t stream)
{
    const float* x   = (const float*)d_in[0];
    const float* Wq  = (const float*)d_in[1];
    const float* bq  = (const float*)d_in[2];
    const float* Wk  = (const float*)d_in[3];
    const float* bk  = (const float*)d_in[4];
    const float* Wv  = (const float*)d_in[5];
    const float* bv  = (const float*)d_in[6];
    const float* Wfc = (const float*)d_in[7];
    const float* bfc = (const float*)d_in[8];
    float* out = (float*)d_out;

    char* ws = (char*)d_ws;
    f16*   Qh    = (f16*)(ws + QH_OFF);
    f16*   Kh    = (f16*)(ws + KH_OFF);
    f16*   Vt    = (f16*)(ws + VT_OFF);
    f16*   Opart = (f16*)(ws + OP_OFF);
    float* Ml    = (float*)(ws + ML_OFF);

    proj_kernel<<<dim3(256, 3), 256, 0, stream>>>(x, Wq, Wk, Wv, bq, bk, bv, Qh, Kh, Vt);
    attn_kernel<<<512, 256, 0, stream>>>(Qh, Kh, Vt, Opart, Ml);
    merge_fc_kernel<<<512, 256, 0, stream>>>(Opart, Ml, Wfc, bfc, out);
}

// Round 6
// 207.691 us; speedup vs baseline: 1.1545x; 1.0396x over previous
//
#include <hip/hip_runtime.h>
#include <stdint.h>

// Problem constants
#define B_ 4
#define N_ 4096
#define D_ 256
#define M_ (B_*N_)   // 16384

typedef _Float16 f16;
typedef _Float16 f16x8 __attribute__((ext_vector_type(8)));
typedef float    f32x4  __attribute__((ext_vector_type(4)));
typedef float    f32x16 __attribute__((ext_vector_type(16)));

#define MFMA16(A,B,C) __builtin_amdgcn_mfma_f32_16x16x32_f16(A,B,C,0,0,0)
#define MFMA32(A,B,C) __builtin_amdgcn_mfma_f32_32x32x16_f16(A,B,C,0,0,0)

// workspace layout (bytes)
#define QH_OFF   0u            // Qh:   16384*256*2 = 8388608
#define KH_OFF   8388608u      // Kh:   8388608 (PRE-SWIZZLED)
#define VT_OFF   16777216u     // Vt:   [4][256][4096] f16 = 8388608
#define WFCH_OFF 25165824u     // Wfch: 131072 (DMA image, 8 slabs x 16KB)
#define WQS_OFF  25296896u     // Wqs:  262144 (DMA image, hi|lo per dc-slab)
#define WKS_OFF  25559040u
#define WVS_OFF  25821184u
#define OP_OFF   26083328u     // Opart: f16 [4][16384][256] = 33554432
#define ML_OFF   59637760u     // Ml: f32 [4][16384][2] = 524288

typedef __attribute__((address_space(3))) uint32_t lds_u32;
typedef __attribute__((address_space(1))) const uint32_t g_u32;

__device__ __forceinline__ void stage16(const f16* g, f16* lbase) {
    __builtin_amdgcn_global_load_lds((g_u32*)g, (lds_u32*)lbase, 16, 0, 0);
}
__device__ __forceinline__ uint32_t pk2(float a, float b) {
    union { f16 h[2]; uint32_t u; } x;
    x.h[0] = (f16)a; x.h[1] = (f16)b;
    return x.u;
}

// ---------------------------------------------------------------------------
// Kernel 1: weight conversion.
// z<3: DMA image:  (col e, k) -> Ws[(k>>5)*16384 + t*8192 + e*32 + p*8 + (k&7)]
//   t=0 hi / 1 lo, p = ((k>>3)&3) ^ ((e>>2)&3).
// z==3: Wfc -> SAME image, single precision: 8 slabs x 8192 f16.
// ---------------------------------------------------------------------------
__global__ __launch_bounds__(256) void cvt_w(
    const float* __restrict__ Wq, const float* __restrict__ Wk,
    const float* __restrict__ Wv, const float* __restrict__ Wfc,
    f16* __restrict__ Wqs, f16* __restrict__ Wks, f16* __restrict__ Wvs,
    f16* __restrict__ Wfch)
{
    const int z = blockIdx.y;
    const float* W = (z==0) ? Wq : (z==1) ? Wk : (z==2) ? Wv : Wfc;
    int idx = (blockIdx.x * 256 + threadIdx.x) * 4;
    float4 v = *(const float4*)(W + idx);
    union { ushort4 u4; f16 h[4]; } hi, lo;
    float vv[4] = {v.x, v.y, v.z, v.w};
    #pragma unroll
    for (int j = 0; j < 4; j++) {
        hi.h[j] = (f16)vv[j];
        lo.h[j] = (f16)(vv[j] - (float)hi.h[j]);
    }
    int col = idx >> 8, k = idx & 255;
    int dc = k >> 5, c8 = (k >> 3) & 3, j = k & 7;
    int p  = c8 ^ ((col >> 2) & 3);
    if (z == 3) {
        *(ushort4*)(Wfch + dc*8192 + col*32 + p*8 + j) = hi.u4;
    } else {
        f16* Ws = (z==0) ? Wqs : (z==1) ? Wks : Wvs;
        int base = dc*16384 + col*32 + p*8 + j;
        *(ushort4*)(Ws + base)        = hi.u4;
        *(ushort4*)(Ws + base + 8192) = lo.u4;
    }
}

// ---------------------------------------------------------------------------
// Kernel 2: QKV projection (f16 MFMA hi/lo), LDS-staged B (verified R9 form).
// ---------------------------------------------------------------------------
__global__ __launch_bounds__(256, 2) void proj_kernel(
    const float* __restrict__ x,
    const f16* __restrict__ Wqs, const f16* __restrict__ Wks,
    const f16* __restrict__ Wvs,
    const float* __restrict__ bq, const float* __restrict__ bk,
    const float* __restrict__ bv,
    f16* __restrict__ Qh, f16* __restrict__ Kh, f16* __restrict__ Vt)
{
    const int z = blockIdx.y;
    const f16*   Ws   = (z==0) ? Wqs : (z==1) ? Wks : Wvs;
    const float* bias = (z==0) ? bq  : (z==1) ? bk  : bv;

    __shared__ __align__(16) f16 Bs[2][16384];   // 64KB dbuf; VTs union below

    const int tid  = threadIdx.x;
    const int w    = tid >> 6;
    const int lane = tid & 63;
    const int l15  = lane & 15;
    const int q4   = lane >> 4;
    const int m0   = blockIdx.x * 64 + w * 16;
    const int rowA = m0 + l15;
    const int sw   = (l15 >> 2) & 3;             // B read swizzle key

    int s8[8];
    #pragma unroll
    for (int i = 0; i < 8; i++) s8[i] = (tid + i*256) * 8;

    f32x4 acc[16];
    #pragma unroll
    for (int nt = 0; nt < 16; nt++) acc[nt] = (f32x4){0.f,0.f,0.f,0.f};

    // prologue: DMA slab 0, load x chunk 0
    #pragma unroll
    for (int i = 0; i < 8; i++) stage16(Ws + s8[i], &Bs[0][0] + s8[i]);
    const float* xp = x + (size_t)rowA * 256;
    float4 a0 = *(const float4*)(xp + q4*8);
    float4 a1 = *(const float4*)(xp + q4*8 + 4);

    for (int dc = 0; dc < 8; dc++) {
        const int cur = dc & 1;
        __syncthreads();                         // drains DMA(dc); prev reads done
        if (dc < 7) {                            // DMA slab dc+1
            const f16* src = Ws + (size_t)(dc+1)*16384;
            f16* dst = &Bs[cur ^ 1][0];
            #pragma unroll
            for (int i = 0; i < 8; i++) stage16(src + s8[i], dst + s8[i]);
        }
        float av[8] = {a0.x,a0.y,a0.z,a0.w,a1.x,a1.y,a1.z,a1.w};
        f16x8 ah, alo;
        #pragma unroll
        for (int j = 0; j < 8; j++) {
            ah[j]  = (f16)av[j];
            alo[j] = (f16)(av[j] - (float)ah[j]);
        }
        if (dc < 7) {                            // prefetch next x chunk
            a0 = *(const float4*)(xp + (dc+1)*32 + q4*8);
            a1 = *(const float4*)(xp + (dc+1)*32 + q4*8 + 4);
        }
        const f16* Bc = &Bs[cur][0];
        #pragma unroll
        for (int nt = 0; nt < 16; nt++) {
            const f16* bp = Bc + (nt*16 + l15)*32 + ((q4 ^ sw) << 3);
            f16x8 bh = *(const f16x8*)bp;
            f16x8 bl = *(const f16x8*)(bp + 8192);
            acc[nt] = MFMA16(ah,  bl, acc[nt]);
            acc[nt] = MFMA16(alo, bh, acc[nt]);
            acc[nt] = MFMA16(ah,  bh, acc[nt]);
        }
    }

    if (z == 0) {
        #pragma unroll
        for (int nt = 0; nt < 16; nt++) {
            float bb = bias[nt*16 + l15];
            #pragma unroll
            for (int r = 0; r < 4; r++)
                Qh[(size_t)(m0 + q4*4 + r)*256 + nt*16 + l15] = (f16)(acc[nt][r] + bb);
        }
    } else if (z == 1) {
        // swizzled Kh image for attn's DMA staging
        const int cbase = (l15 >> 3);
        const int j     = l15 & 7;
        #pragma unroll
        for (int nt = 0; nt < 16; nt++) {
            float bb = bias[nt*16 + l15];
            int c = nt*2 + cbase;
            #pragma unroll
            for (int r = 0; r < 4; r++) {
                int m = m0 + q4*4 + r;
                Kh[(size_t)m*256 + (size_t)((c ^ (m & 7)) << 3) + j] = (f16)(acc[nt][r] + bb);
            }
        }
    } else {
        // V: transpose through LDS (unions with Bs), coalesced b128 stores
        uint32_t* VTs = (uint32_t*)&Bs[0][0];
        const int bb_ = m0 >> 12;
        const int n0  = (blockIdx.x * 64) & 4095;
        const int mloc = w*16 + q4*4;
        const int mc   = mloc >> 3;
        __syncthreads();
        #pragma unroll
        for (int nt = 0; nt < 16; nt++) {
            int e = nt*16 + l15;
            float bv_ = bias[e];
            uint32_t w0 = pk2(acc[nt][0]+bv_, acc[nt][1]+bv_);
            uint32_t w1 = pk2(acc[nt][2]+bv_, acc[nt][3]+bv_);
            int base = e*36 + ((mc ^ (e & 7)) << 2) + ((q4*2) & 3);
            VTs[base]     = w0;
            VTs[base + 1] = w1;
        }
        __syncthreads();
        #pragma unroll
        for (int i = 0; i < 8; i++) {
            int e  = w*64 + i*8 + (lane >> 3);
            int nc = lane & 7;
            const f16* src = (const f16*)&VTs[e*36 + ((nc ^ (e & 7)) << 2)];
            f16x8 v = *(const f16x8*)src;
            *(f16x8*)(Vt + ((size_t)bb_*256 + e)*4096 + n0 + nc*8) = v;
        }
    }
}

// ---------------------------------------------------------------------------
// Kernel 3: flash attention, TRANSPOSED compute with 32x32x16 MFMA.
// Verified R9 body. Structural floor ~95us: serial per-iter critical path
// ~5.2k cyc (measured via R13 1-wave/SIMD probe), hidden 73% by 2 waves/SIMD;
// deeper hiding blocked by regs (256/wave x 2 = full 512/SIMD pool) and LDS
// read BW (~2.6k cyc/iter at 2 blocks/CU). Do not restructure without
// simultaneously cutting per-wave state <128 regs AND LDS <48KB (see R10/R13).
// ---------------------------------------------------------------------------
#define MARGIN 10.0f
__global__ __launch_bounds__(256, 2) void attn_kernel(
    const f16* __restrict__ Qh, const f16* __restrict__ Kh,
    const f16* __restrict__ Vt,
    f16* __restrict__ Opart, float* __restrict__ Ml)
{
    __shared__ __align__(16) f16 SMEM[32768];     // Ks[2][8192] | Vs[2][8192]
    f16* Ks = SMEM;
    f16* Vs = SMEM + 16384;

    const int combo = blockIdx.x & 15;
    const int b   = combo >> 2;
    const int sp  = combo & 3;
    const int qt  = blockIdx.x >> 4;              // 0..31
    const int tid  = threadIdx.x;
    const int w    = tid >> 6;
    const int lane = tid & 63;
    const int l31  = lane & 31;                   // q column
    const int half = lane >> 5;
    const int qbase = qt * 128 + w * 32;          // wave's q-row base (incl. w)
    const int vx   = (l31 >> 2) & 3;              // V image swizzle key

    // Q as B-frags (16 steps of d): lane holds Q[q][8d]
    f16x8 qf[16];
    {
        const f16* qp = Qh + ((size_t)(b*4096 + qbase + l31))*256 + half*8;
        #pragma unroll
        for (int st = 0; st < 16; st++) qf[st] = *(const f16x8*)(qp + st*16);
    }

    f32x16 Oa[8];                                 // O^T d-tiles (C-layout)
    #pragma unroll
    for (int t = 0; t < 8; t++)
        #pragma unroll
        for (int r = 0; r < 16; r++) Oa[t][r] = 0.f;
    float mo = -3e38f, ls = 0.f;                  // per-lane (q = l31)

    const f16* kg0 = Kh + ((size_t)(b*4096 + sp*1024)) * 256;   // swizzled
    const f16* vg0 = Vt + ((size_t)b*256) * 4096 + sp*1024;

    int kslot[4], voff[4];
    #pragma unroll
    for (int i = 0; i < 4; i++) {
        int s = tid + i*256;
        kslot[i] = s * 8;
        int d = s >> 2;
        int kc = (s & 3) ^ ((s >> 4) & 3);        // image: pos = kc ^ ((d>>2)&3)
        voff[i] = d * 4096 + kc * 8;
    }

    // prologue: DMA K(0)
    #pragma unroll
    for (int i = 0; i < 4; i++) stage16(kg0 + kslot[i], Ks + kslot[i]);

    f16x8 bp0, bp1;                               // carried P^T B-frags

    for (int it = 0; it < 32; it++) {
        const int cur = it & 1;
        __syncthreads();                          // drains K(t), V(t-1) DMAs
        if (it + 1 < 32) {
            const f16* kg = kg0 + (size_t)(it+1) * 8192;
            f16* kl = Ks + (cur ^ 1) * 8192;
            #pragma unroll
            for (int i = 0; i < 4; i++) stage16(kg + kslot[i], kl + kslot[i]);
        }
        {
            const f16* vg = vg0 + it*32;
            f16* vl = Vs + cur * 8192;
            #pragma unroll
            for (int i = 0; i < 4; i++) stage16(vg + voff[i], vl + kslot[i]);
        }

        // S^T(t) interleaved with PV(t-1): 32 MFMAs
        const f16* krp = Ks + cur*8192 + l31*256;
        const f16* vpp = Vs + (cur^1)*8192 + l31*32;
        f32x16 sa;
        #pragma unroll
        for (int r = 0; r < 16; r++) sa[r] = 0.f;
        if (it > 0) {
            #pragma unroll
            for (int st = 0; st < 16; st++) {
                f16x8 ka = *(const f16x8*)(krp + (((st*2 + half) ^ (lane & 7)) << 3));
                sa = MFMA32(ka, qf[st], sa);
                int t = st >> 1, kh = st & 1;
                f16x8 va = *(const f16x8*)(vpp + t*1024 + (((half + kh*2) ^ vx) << 3));
                Oa[t] = MFMA32(va, kh ? bp1 : bp0, Oa[t]);
            }
        } else {
            #pragma unroll
            for (int st = 0; st < 16; st++) {
                f16x8 ka = *(const f16x8*)(krp + (((st*2 + half) ^ (lane & 7)) << 3));
                sa = MFMA32(ka, qf[st], sa);
            }
        }

        // per-lane hysteresis softmax (q = lane col)
        float tm = sa[0];
        #pragma unroll
        for (int r = 1; r < 16; r++) tm = fmaxf(tm, sa[r]);
        if (__any(tm > mo + MARGIN)) {
            float tmq = fmaxf(tm, __shfl_xor(tm, 32));
            float mn = fmaxf(mo, tmq);
            float al = __expf(mo - mn);
            mo = mn; ls *= al;
            #pragma unroll
            for (int t = 0; t < 8; t++)
                #pragma unroll
                for (int r = 0; r < 16; r++) Oa[t][r] *= al;
        }
        float p[16];
        #pragma unroll
        for (int r = 0; r < 16; r++) { p[r] = __expf(sa[r] - mo); ls += p[r]; }

        // build P^T B-frags: keys 16kh + [0..7](h=0) / [8..15](h=1)
        #pragma unroll
        for (int kh = 0; kh < 2; kh++) {
            uint32_t lo0 = pk2(p[8*kh+0], p[8*kh+1]);
            uint32_t lo1 = pk2(p[8*kh+2], p[8*kh+3]);
            uint32_t hi0 = pk2(p[8*kh+4], p[8*kh+5]);
            uint32_t hi1 = pk2(p[8*kh+6], p[8*kh+7]);
            uint32_t s0 = half ? lo0 : hi0;
            uint32_t s1 = half ? lo1 : hi1;
            uint32_t r0 = __shfl_xor(s0, 32);
            uint32_t r1 = __shfl_xor(s1, 32);
            uint32_t k0 = half ? hi0 : lo0;
            uint32_t k1 = half ? hi1 : lo1;
            union { uint32_t u[4]; f16x8 v; } bb;
            bb.u[0] = half ? r0 : k0;
            bb.u[1] = half ? r1 : k1;
            bb.u[2] = half ? k0 : r0;
            bb.u[3] = half ? k1 : r1;
            if (kh == 0) bp0 = bb.v; else bp1 = bb.v;
        }
    }

    // final PV(31): drain V(31) DMA, then consume
    __syncthreads();
    {
        const f16* vpp = Vs + 8192 + l31*32;      // V(31) in Vs[1]
        #pragma unroll
        for (int t = 0; t < 8; t++) {
            #pragma unroll
            for (int kh = 0; kh < 2; kh++) {
                f16x8 va = *(const f16x8*)(vpp + t*1024 + (((half + kh*2) ^ vx) << 3));
                Oa[t] = MFMA32(va, kh ? bp1 : bp0, Oa[t]);
            }
        }
    }
    __syncthreads();                              // all waves done with SMEM tiles

    // epilogue: l across half-pair, normalize, un-transpose via per-wave LDS
    float l = ls + __shfl_xor(ls, 32);
    float inv = 1.0f / l;
    f16* tb = SMEM + w * 8192;                    // 16KB per wave
    #pragma unroll
    for (int t = 0; t < 8; t++) {
        #pragma unroll
        for (int rp = 0; rp < 8; rp++) {
            int r0 = rp * 2;
            int d  = (r0 & 3) + 8*(r0 >> 2) + 4*half + t*32;
            int c  = d >> 3, j = d & 7;
            uint32_t wv = pk2(Oa[t][r0]*inv, Oa[t][r0+1]*inv);
            *(uint32_t*)(tb + l31*256 + ((c ^ (l31 & 7)) << 3) + (j & 6)) = wv;
        }
    }
    // coalesced read-back + global store (per-wave region, rows = qbase+q)
    f16* opb = Opart + ((size_t)sp*M_ + b*4096 + qbase) * 256;
    #pragma unroll
    for (int i = 0; i < 16; i++) {
        int q = (i & 3)*8 + (lane >> 3);
        int c = (i >> 2)*8 + (lane & 7);
        f16x8 v = *(const f16x8*)(tb + q*256 + ((c ^ (q & 7)) << 3));
        *(f16x8*)(opb + (size_t)q*256 + c*8) = v;
    }
    if (half == 0) {
        size_t mrow = (size_t)sp*M_ + b*4096 + qbase + l31;
        Ml[mrow*2]     = mo;
        Ml[mrow*2 + 1] = l;
    }
}

// ---------------------------------------------------------------------------
// Kernel 4: merge 4 normalized k-quarter partials + FC + bias.
// Wfc B-frags staged via global_load_lds double-buffered LDS; Opart
// fragments prefetched one dc ahead. (Verified R9 form.)
// ---------------------------------------------------------------------------
__global__ __launch_bounds__(256, 2) void merge_fc_kernel(
    const f16* __restrict__ Opart, const float* __restrict__ Ml,
    const f16* __restrict__ Wfci, const float* __restrict__ bfc,
    float* __restrict__ out)
{
    __shared__ __align__(16) f16 Bs[2][8192];    // 2 x 16KB slabs

    const int tid  = threadIdx.x;
    const int w    = tid >> 6;
    const int lane = tid & 63;
    const int l15  = lane & 15;
    const int q4   = lane >> 4;
    const int m0   = blockIdx.x * 64 + w * 16;
    const int rowA = m0 + l15;
    const int sw   = (l15 >> 2) & 3;             // B read swizzle key

    int s4[4];
    #pragma unroll
    for (int i = 0; i < 4; i++) s4[i] = (tid + i*256) * 8;

    float mv[4], lv[4];
    #pragma unroll
    for (int p = 0; p < 4; p++) {
        mv[p] = Ml[((size_t)p*M_ + rowA)*2];
        lv[p] = Ml[((size_t)p*M_ + rowA)*2 + 1];
    }
    float mm = fmaxf(fmaxf(mv[0], mv[1]), fmaxf(mv[2], mv[3]));
    float cw[4], den = 0.f;
    #pragma unroll
    for (int p = 0; p < 4; p++) { cw[p] = __expf(mv[p] - mm) * lv[p]; den += cw[p]; }
    float invd = 1.0f / den;
    #pragma unroll
    for (int p = 0; p < 4; p++) cw[p] *= invd;

    // prologue: DMA slab 0, prefetch Opart frags for dc=0
    #pragma unroll
    for (int i = 0; i < 4; i++) stage16(Wfci + s4[i], &Bs[0][0] + s4[i]);
    const f16* opb = Opart + (size_t)rowA*256 + q4*8;
    f16x8 of[4];
    #pragma unroll
    for (int p = 0; p < 4; p++) of[p] = *(const f16x8*)(opb + (size_t)p*M_*256);

    f32x4 acc[16];
    #pragma unroll
    for (int nt = 0; nt < 16; nt++) acc[nt] = (f32x4){0.f,0.f,0.f,0.f};

    for (int dc = 0; dc < 8; dc++) {
        const int cur = dc & 1;
        __syncthreads();                         // drains DMA(dc); prev reads done
        if (dc < 7) {
            const f16* src = Wfci + (size_t)(dc+1)*8192;
            f16* dst = &Bs[cur ^ 1][0];
            #pragma unroll
            for (int i = 0; i < 4; i++) stage16(src + s4[i], dst + s4[i]);
        }
        // weighted merge of the 4 partials -> A-frag
        float v[8] = {};
        #pragma unroll
        for (int p = 0; p < 4; p++)
            #pragma unroll
            for (int j = 0; j < 8; j++) v[j] += cw[p] * (float)of[p][j];
        f16x8 af;
        #pragma unroll
        for (int j = 0; j < 8; j++) af[j] = (f16)v[j];
        if (dc < 7) {                            // prefetch next Opart frags
            #pragma unroll
            for (int p = 0; p < 4; p++)
                of[p] = *(const f16x8*)(opb + (size_t)p*M_*256 + (dc+1)*32);
        }
        const f16* Bc = &Bs[cur][0];
        #pragma unroll
        for (int nt = 0; nt < 16; nt++) {
            f16x8 bf = *(const f16x8*)(Bc + (nt*16 + l15)*32 + ((q4 ^ sw) << 3));
            acc[nt] = MFMA16(af, bf, acc[nt]);
        }
    }
    #pragma unroll
    for (int nt = 0; nt < 16; nt++) {
        float bias = bfc[nt*16 + l15];
        #pragma unroll
        for (int r = 0; r < 4; r++)
            out[(size_t)(m0 + q4*4 + r) * 256 + nt*16 + l15] = acc[nt][r] + bias;
    }
}

// ---------------------------------------------------------------------------
extern "C" void kernel_launch(void* const* d_in, const int* in_sizes, int n_in,
                              void* d_out, int out_size, void* d_ws, size_t ws_size,
                              hipStream_t stream)
{
    const float* x   = (const float*)d_in[0];
    const float* Wq  = (const float*)d_in[1];
    const float* bq  = (const float*)d_in[2];
    const float* Wk  = (const float*)d_in[3];
    const float* bk  = (const float*)d_in[4];
    const float* Wv  = (const float*)d_in[5];
    const float* bv  = (const float*)d_in[6];
    const float* Wfc = (const float*)d_in[7];
    const float* bfc = (const float*)d_in[8];
    float* out = (float*)d_out;

    char* ws = (char*)d_ws;
    f16*   Qh    = (f16*)(ws + QH_OFF);
    f16*   Kh    = (f16*)(ws + KH_OFF);
    f16*   Vt    = (f16*)(ws + VT_OFF);
    f16*   Wfch  = (f16*)(ws + WFCH_OFF);
    f16*   Wqs   = (f16*)(ws + WQS_OFF);
    f16*   Wks   = (f16*)(ws + WKS_OFF);
    f16*   Wvs   = (f16*)(ws + WVS_OFF);
    f16*   Opart = (f16*)(ws + OP_OFF);
    float* Ml    = (float*)(ws + ML_OFF);

    cvt_w<<<dim3(64, 4), 256, 0, stream>>>(Wq, Wk, Wv, Wfc, Wqs, Wks, Wvs, Wfch);
    proj_kernel<<<dim3(256, 3), 256, 0, stream>>>(x, Wqs, Wks, Wvs, bq, bk, bv, Qh, Kh, Vt);
    attn_kernel<<<512, 256, 0, stream>>>(Qh, Kh, Vt, Opart, Ml);
    merge_fc_kernel<<<256, 256, 0, stream>>>(Opart, Ml, Wfch, bfc, out);
}